// Round 7
// baseline (425.465 us; speedup 1.0000x reference)
//
#include <hip/hip_runtime.h>

#define N_NODES 50000
#define N_EDGES 800000
#define HID 128

typedef _Float16 f16;
typedef _Float16 half8 __attribute__((ext_vector_type(8)));
typedef _Float16 half4 __attribute__((ext_vector_type(4)));
typedef _Float16 half2v __attribute__((ext_vector_type(2)));
typedef float f32x4 __attribute__((ext_vector_type(4)));
typedef float f32x2 __attribute__((ext_vector_type(2)));

// ---- CSR-path workspace layout (bytes). P (f16 [50000][256]) lives in d_out. ----
#define OFF_MI     0UL             // 50000*128*4 = 25,600,000 (f32 aggregate, zeroed in pack)
#define OFF_H16C   25600000UL      // 12,800,000
#define OFF_WC     38400000UL      // packed weights: 204,800
#define OFF_CNT    38604800UL      // 50176*4 = 200,704
#define OFF_CUR    38805504UL      // 200,704
#define OFF_E4     39006208UL      // 800000*16 = 12,800,000  (CSR-ordered {eid,dst,src,pad})
#define CSR_TOTAL  51806208UL

// ---- fallback (atomic-path) layout ----
#define OFF_FMI  0UL
#define OFF_FH16 25600000UL
#define OFF_FW   38400000UL

#define WB1 0
#define WB2 36864
#define WN1 53248
#define WN2 86016

#define TS 136   // S16/T tile stride (f16)
#define YS 264   // node Y tile stride (256 + pad)
#define AS 40    // attr tile stride (f16): 24 attr + 8 zero + pad

#define EB 32    // edges per block (32 -> ~12KB LDS -> 8 blocks/CU; R6 showed 64 regresses)
#define NB 32    // nodes per block for precompute/node

// pack weights into B-fragment layout; zero cnt and mi
__global__ __launch_bounds__(256) void pack_weights(
    const float* __restrict__ We1, const float* __restrict__ We2,
    const float* __restrict__ Wn1, const float* __restrict__ Wn2,
    f16* __restrict__ W, int* __restrict__ cnt, float* __restrict__ mi) {
  int i = blockIdx.x * 256 + threadIdx.x;   // 0..102399
  if (cnt && i < 50176) cnt[i] = 0;
  if (mi) {
    f32x4 z = {0.f, 0.f, 0.f, 0.f};
    for (int j = i; j < N_NODES * HID / 4; j += 102400)
      ((f32x4*)mi)[j] = z;
  }
  if (i < 36864) {                          // We1 (rows permuted: h first, attr last)
    int j = i & 7, n = (i >> 3) & 127, qk = i >> 10;
    int k = qk * 8 + j;
    float v = 0.f;
    if (k < 256) v = We1[(24 + k) * 128 + n];
    else if (k < 280) v = We1[(k - 256) * 128 + n];
    W[WB1 + i] = (f16)v;
  } else if (i < 53248) {                   // We2
    int l = i - 36864;
    int j = l & 7, n = (l >> 3) & 127, qk = l >> 10;
    W[WB2 + l] = (f16)We2[(qk * 8 + j) * 128 + n];
  } else if (i < 86016) {                   // Wn1
    int l = i - 53248;
    int j = l & 7, n = (l >> 3) & 127, qk = l >> 10;
    W[WN1 + l] = (f16)Wn1[(qk * 8 + j) * 128 + n];
  } else if (i < 102400) {                  // Wn2
    int l = i - 86016;
    int j = l & 7, n = (l >> 3) & 127, qk = l >> 10;
    W[WN2 + l] = (f16)Wn2[(qk * 8 + j) * 128 + n];
  }
}

// ==== single-kernel coalesced scan of cnt[50176] -> cur (exclusive prefix).
//      49 blocks; block b redundantly sums cnt[0..b*1024) (coalesced, tiny) for its base. ====
__global__ __launch_bounds__(256) void scan_kernel(const int* __restrict__ cnt,
                                                   int* __restrict__ cur) {
  __shared__ int red[4];
  __shared__ int wsum[4];
  int t = threadIdx.x, b = blockIdx.x;
  int lane = t & 63, w = t >> 6;
  // base = sum cnt[0 .. b*1024)
  int s0 = 0;
  for (int i = t * 4; i < b * 1024; i += 1024) {
    int4 v = *(const int4*)(cnt + i);
    s0 += v.x + v.y + v.z + v.w;
  }
  #pragma unroll
  for (int off = 32; off; off >>= 1) s0 += __shfl_down(s0, off, 64);
  if (lane == 0) red[w] = s0;
  __syncthreads();
  int base_all = red[0] + red[1] + red[2] + red[3];
  // local exclusive scan of our 1024 chunk
  int base = b * 1024 + t * 4;
  int4 v = *(const int4*)(cnt + base);
  int s = v.x + v.y + v.z + v.w;
  int inc = s;
  #pragma unroll
  for (int off = 1; off < 64; off <<= 1) {
    int u = __shfl_up(inc, off, 64);
    if (lane >= off) inc += u;
  }
  if (lane == 63) wsum[w] = inc;
  __syncthreads();
  int wbase = 0;
  for (int i = 0; i < w; ++i) wbase += wsum[i];
  int excl = base_all + wbase + inc - s;
  int4 o;
  o.x = excl; o.y = excl + v.x; o.z = o.y + v.y; o.w = o.z + v.z;
  *(int4*)(cur + base) = o;
}

// CSR edge records: e4[csr_pos] = {edge id, dst, src, 0}
__global__ __launch_bounds__(256) void fill_perm(
    const int* __restrict__ eidx, int* __restrict__ cur, int4* __restrict__ e4) {
  int i = blockIdx.x * 256 + threadIdx.x;   // 0..799999 exactly
  int d = eidx[i];
  int s = eidx[N_EDGES + i];
  int p = atomicAdd(&cur[d], 1);
  int4 rec; rec.x = i; rec.y = d; rec.z = s; rec.w = 0;
  e4[p] = rec;
}

// ==== precompute (32 nodes/block): h f32->f16 (writes h16), degree histogram,
//      P[n][0:128] = h[n]@We1[24:152], P[n][128:256] = h[n]@We1[152:280] (f16). ====
__global__ __launch_bounds__(256, 8) void precompute_kernel(
    const float* __restrict__ h, const int* __restrict__ eidx,
    const f16* __restrict__ Wp, f16* __restrict__ P,
    f16* __restrict__ h16, int* __restrict__ cnt) {
  __shared__ f16 Y[NB * 136];   // 8,704B
  int t = threadIdx.x;
  int n0 = blockIdx.x * NB;
  {
    int rb = t >> 4, ch = t & 15;
    #pragma unroll
    for (int p = 0; p < 2; ++p) {
      int r = p * 16 + rb;
      int g = n0 + r; if (g >= N_NODES) g = N_NODES - 1;
      const float4* s4 = (const float4*)(h + (size_t)g * HID + ch * 8);
      float4 a = s4[0], b = s4[1];
      half8 v = {(f16)a.x, (f16)a.y, (f16)a.z, (f16)a.w,
                 (f16)b.x, (f16)b.y, (f16)b.z, (f16)b.w};
      *(half8*)&Y[r * 136 + ch * 8] = v;
      *(half8*)(h16 + (size_t)g * HID + ch * 8) = v;
    }
  }
  // fused degree histogram (grid-stride over edges)
  if (cnt) {
    for (int i = blockIdx.x * 256 + t; i < N_EDGES; i += gridDim.x * 256)
      atomicAdd(&cnt[eidx[i]], 1);
  }
  __syncthreads();
  int w = t >> 6, lane = t & 63, q = lane >> 4, c = lane & 15;
  int colBase = w * 32;
  const f16* B = Wp + WB1 + ((size_t)(q * 128 + colBase + c)) * 8;
  f32x4 aD[2][2], aS[2][2];
  #pragma unroll
  for (int mt = 0; mt < 2; ++mt) {
    aD[mt][0] = (f32x4){0, 0, 0, 0}; aD[mt][1] = (f32x4){0, 0, 0, 0};
    aS[mt][0] = (f32x4){0, 0, 0, 0}; aS[mt][1] = (f32x4){0, 0, 0, 0};
  }
  #pragma unroll
  for (int ks = 0; ks < 4; ++ks) {
    half8 bD0 = *(const half8*)(B + ks * 4096);
    half8 bD1 = *(const half8*)(B + ks * 4096 + 128);
    half8 bS0 = *(const half8*)(B + (ks + 4) * 4096);
    half8 bS1 = *(const half8*)(B + (ks + 4) * 4096 + 128);
    #pragma unroll
    for (int mt = 0; mt < 2; ++mt) {
      half8 a = *(const half8*)&Y[(mt * 16 + c) * 136 + ks * 32 + q * 8];
      aD[mt][0] = __builtin_amdgcn_mfma_f32_16x16x32_f16(a, bD0, aD[mt][0], 0, 0, 0);
      aD[mt][1] = __builtin_amdgcn_mfma_f32_16x16x32_f16(a, bD1, aD[mt][1], 0, 0, 0);
      aS[mt][0] = __builtin_amdgcn_mfma_f32_16x16x32_f16(a, bS0, aS[mt][0], 0, 0, 0);
      aS[mt][1] = __builtin_amdgcn_mfma_f32_16x16x32_f16(a, bS1, aS[mt][1], 0, 0, 0);
    }
  }
  #pragma unroll
  for (int mt = 0; mt < 2; ++mt)
    #pragma unroll
    for (int r = 0; r < 4; ++r) {
      int g = n0 + mt * 16 + q * 4 + r;
      if (g < N_NODES) {
        f16* o = P + (size_t)g * 256 + colBase + c;
        o[0]        = (f16)aD[mt][0][r];
        o[16]       = (f16)aD[mt][1][r];
        o[128]      = (f16)aS[mt][0][r];
        o[128 + 16] = (f16)aS[mt][1][r];
      }
    }
}

// ==== edge kernel (32 edges/block, XCD-swizzled blocks): CSR-ordered e4 records.
//      Layer1 = attr@Wa (K=32 MFMA) + f16 (Pd[dst]+Ps[src]) packed adds.
//      Epilogue: vectorized half2 run-reduction -> paired f32 atomicAdd into mi. ====
__global__ __launch_bounds__(256, 8) void edge_kernel(
    const f16* __restrict__ P, const int* __restrict__ eidx,
    const float* __restrict__ eattr,
    const f16* __restrict__ Wp, const float* __restrict__ be1,
    const float* __restrict__ be2,
    const float* __restrict__ Wg, const float* __restrict__ bg,
    float* __restrict__ mi, const int4* __restrict__ e4) {
  __shared__ f16 S16[EB * TS];       // 8,704B  (f16 Pd+Ps sums; T aliases this)
  __shared__ f16 A[EB * AS];         // 2,560B  (attr, 24 + 8 zeros)
  __shared__ float part[EB * 4];
  __shared__ float eijL[EB];
  __shared__ int dstL[EB];
  int t = threadIdx.x;
  // XCD-aware swizzle: 25000 blocks = 8 XCDs x 3125 contiguous CSR chunks each.
  // Keeps each XCD's dst-P rows (~3.2MB) and mi atomic range (~3.2MB) in its own 4MB L2.
  int bid = (blockIdx.x & 7) * 3125 + (blockIdx.x >> 3);
  int e0 = bid * EB;

  if (t < EB) dstL[t] = e4 ? e4[e0 + t].y : eidx[e0 + t];

  // ---- stage S16 = Pd[dst] + Ps[src] (f16, packed adds) ----
  {
    int rb = t >> 4, ch = t & 15;
    #pragma unroll
    for (int p = 0; p < 2; ++p) {
      int r = p * 16 + rb;
      int d, s;
      if (e4) {
        int4 rec = e4[e0 + r];       // 16B broadcast across the 16 lanes of this row
        d = rec.y; s = rec.z;
      } else {
        d = eidx[e0 + r]; s = eidx[N_EDGES + e0 + r];
      }
      half8 pd = *(const half8*)(P + (size_t)d * 256 + ch * 8);
      half8 ps = *(const half8*)(P + (size_t)s * 256 + 128 + ch * 8);
      *(half8*)&S16[r * TS + ch * 8] = pd + ps;
    }
  }
  // ---- stage edge_attr (cols 0..23), zeros 24..31 ----
  if (t < 192) {
    int el = t / 6, kk = t % 6;
    int e = e4 ? e4[e0 + el].x : (e0 + el);
    float4 f = *(const float4*)(eattr + (size_t)e * 24 + kk * 4);
    half4 hv = {(f16)f.x, (f16)f.y, (f16)f.z, (f16)f.w};
    *(half4*)&A[el * AS + kk * 4] = hv;
  }
  if (t < EB) { uint4 z = {0, 0, 0, 0}; *(uint4*)&A[t * AS + 24] = z; }
  __syncthreads();

  int w = t >> 6, lane = t & 63, q = lane >> 4, c = lane & 15;
  int colBase = w * 32;

  // ---- layer 1: attr GEMM (K=32, WB1 block k=256..287) + S16 add ----
  f32x4 acc[2][2];
  {
    float b0 = be1[colBase + c], b1 = be1[colBase + 16 + c];
    #pragma unroll
    for (int mt = 0; mt < 2; ++mt) {
      acc[mt][0] = (f32x4){b0, b0, b0, b0};
      acc[mt][1] = (f32x4){b1, b1, b1, b1};
    }
  }
  {
    const f16* bA = Wp + WB1 + 32768 + ((size_t)(q * 128 + colBase + c)) * 8;
    half8 b0f = *(const half8*)(bA);
    half8 b1f = *(const half8*)(bA + 128);
    #pragma unroll
    for (int mt = 0; mt < 2; ++mt) {
      half8 a = *(const half8*)&A[(mt * 16 + c) * AS + q * 8];
      acc[mt][0] = __builtin_amdgcn_mfma_f32_16x16x32_f16(a, b0f, acc[mt][0], 0, 0, 0);
      acc[mt][1] = __builtin_amdgcn_mfma_f32_16x16x32_f16(a, b1f, acc[mt][1], 0, 0, 0);
    }
  }
  #pragma unroll
  for (int mt = 0; mt < 2; ++mt)
    #pragma unroll
    for (int r = 0; r < 4; ++r) {
      const f16* sr = &S16[(mt * 16 + q * 4 + r) * TS + colBase + c];
      acc[mt][0][r] += (float)sr[0];
      acc[mt][1][r] += (float)sr[16];
    }

  const f16* bp2base = Wp + WB2 + ((size_t)(q * 128 + colBase + c)) * 8;
  half8 d0 = *(const half8*)(bp2base);
  half8 d1 = *(const half8*)(bp2base + 128);

  __syncthreads();
  f16* T = S16;   // alias (S16 dead from here; same stride TS)
  #pragma unroll
  for (int mt = 0; mt < 2; ++mt)
    #pragma unroll
    for (int nt = 0; nt < 2; ++nt)
      #pragma unroll
      for (int r = 0; r < 4; ++r) {
        float v = acc[mt][nt][r];
        T[(mt * 16 + q * 4 + r) * TS + colBase + nt * 16 + c] = (f16)(v > 0.f ? v : 0.f);
      }
  __syncthreads();

  // ---- layer 2 ----
  f32x4 m2[2][2];
  {
    float b0 = be2[colBase + c], b1 = be2[colBase + 16 + c];
    #pragma unroll
    for (int mt = 0; mt < 2; ++mt) {
      m2[mt][0] = (f32x4){b0, b0, b0, b0};
      m2[mt][1] = (f32x4){b1, b1, b1, b1};
    }
  }
  #pragma unroll
  for (int kk = 0; kk < 4; ++kk) {
    half8 n0, n1;
    if (kk < 3) {
      n0 = *(const half8*)(bp2base + (kk + 1) * 4096);
      n1 = *(const half8*)(bp2base + (kk + 1) * 4096 + 128);
    }
    #pragma unroll
    for (int mt = 0; mt < 2; ++mt) {
      half8 a = *(const half8*)&T[(mt * 16 + c) * TS + kk * 32 + q * 8];
      m2[mt][0] = __builtin_amdgcn_mfma_f32_16x16x32_f16(a, d0, m2[mt][0], 0, 0, 0);
      m2[mt][1] = __builtin_amdgcn_mfma_f32_16x16x32_f16(a, d1, m2[mt][1], 0, 0, 0);
    }
    d0 = n0; d1 = n1;
  }

  // ---- relu + gate ----
  float wg0 = Wg[colBase + c], wg1 = Wg[colBase + 16 + c];
  float pd[2][4];
  #pragma unroll
  for (int mt = 0; mt < 2; ++mt)
    #pragma unroll
    for (int r = 0; r < 4; ++r) {
      float v0 = m2[mt][0][r]; v0 = v0 > 0.f ? v0 : 0.f; m2[mt][0][r] = v0;
      float v1 = m2[mt][1][r]; v1 = v1 > 0.f ? v1 : 0.f; m2[mt][1][r] = v1;
      pd[mt][r] = v0 * wg0 + v1 * wg1;
    }
  #pragma unroll
  for (int off = 1; off < 16; off <<= 1)
    #pragma unroll
    for (int mt = 0; mt < 2; ++mt)
      #pragma unroll
      for (int r = 0; r < 4; ++r)
        pd[mt][r] += __shfl_xor(pd[mt][r], off, 64);
  if (c == 0)
    #pragma unroll
    for (int mt = 0; mt < 2; ++mt)
      #pragma unroll
      for (int r = 0; r < 4; ++r)
        part[(mt * 16 + q * 4 + r) * 4 + w] = pd[mt][r];
  __syncthreads();
  if (t < EB) {
    float s = part[t * 4] + part[t * 4 + 1] + part[t * 4 + 2] + part[t * 4 + 3] + bg[0];
    eijL[t] = 1.f / (1.f + __expf(-s));
  }
  __syncthreads();

  if (e4) {
    // ---- write gated rows to T, then vectorized run-reduce -> paired atomicAdd mi ----
    #pragma unroll
    for (int mt = 0; mt < 2; ++mt)
      #pragma unroll
      for (int r = 0; r < 4; ++r) {
        int el = mt * 16 + q * 4 + r;
        float ev = eijL[el];
        T[el * TS + colBase + c]      = (f16)(m2[mt][0][r] * ev);
        T[el * TS + colBase + 16 + c] = (f16)(m2[mt][1][r] * ev);
      }
    __syncthreads();
    // 64 col-pairs x 4 row-groups of 8; partial sums per group are exact under f32 atomics
    int cp = t & 63, grp = t >> 6;
    int r0 = grp * 8;
    float ax = 0.f, ay = 0.f;
    int dprev = dstL[r0];
    #pragma unroll
    for (int r2 = 0; r2 < 8; ++r2) {
      int rr = r0 + r2;
      half2v v = *(const half2v*)&T[rr * TS + 2 * cp];
      ax += (float)v[0]; ay += (float)v[1];
      int dnext = (r2 == 7) ? -1 : dstL[rr + 1];
      if (dnext != dprev) {
        float* base = &mi[(size_t)dprev * HID + 2 * cp];
        atomicAdd(base, ax); atomicAdd(base + 1, ay);
        ax = 0.f; ay = 0.f; dprev = dnext;
      }
    }
  } else {
    #pragma unroll
    for (int mt = 0; mt < 2; ++mt)
      #pragma unroll
      for (int r = 0; r < 4; ++r) {
        int el = mt * 16 + q * 4 + r;
        float ev = eijL[el];
        float* base = mi + (size_t)dstL[el] * HID + colBase + c;
        atomicAdd(base,      m2[mt][0][r] * ev);
        atomicAdd(base + 16, m2[mt][1][r] * ev);
      }
  }
}

// ==== node MLP kernel (32 nodes/block): reads f32 mi (ws) + h16, writes out. ====
__global__ __launch_bounds__(256, 8) void node_kernel(
    const float* __restrict__ mi, const f16* __restrict__ h16,
    const f16* __restrict__ Wp, const float* __restrict__ bn1,
    const float* __restrict__ bn2, float* __restrict__ out) {
  __shared__ f16 Y[NB * YS];   // 16,896B
  int t = threadIdx.x;
  int n0 = blockIdx.x * NB;
  {
    int rb = t >> 4, ch = t & 15;
    #pragma unroll
    for (int p = 0; p < 2; ++p) {
      int r = p * 16 + rb;
      int g = n0 + r; if (g >= N_NODES) g = N_NODES - 1;
      const float4* s = (const float4*)(mi + (size_t)g * HID + ch * 8);
      float4 a = s[0], b = s[1];
      half8 v = {(f16)a.x, (f16)a.y, (f16)a.z, (f16)a.w,
                 (f16)b.x, (f16)b.y, (f16)b.z, (f16)b.w};
      *(half8*)&Y[r * YS + ch * 8] = v;
      *(uint4*)&Y[r * YS + 128 + ch * 8] = *(const uint4*)(h16 + (size_t)g * HID + ch * 8);
    }
  }
  __syncthreads();
  int w = t >> 6, lane = t & 63, q = lane >> 4, c = lane & 15;
  int colBase = w * 32;
  const f16* BN1 = Wp + WN1;
  const f16* BN2 = Wp + WN2;
  f32x4 acc[2][2];
  {
    float b0 = bn1[colBase + c], b1 = bn1[colBase + 16 + c];
    #pragma unroll
    for (int mt = 0; mt < 2; ++mt) {
      acc[mt][0] = (f32x4){b0, b0, b0, b0};
      acc[mt][1] = (f32x4){b1, b1, b1, b1};
    }
  }
  const f16* bn1base = BN1 + ((size_t)(q * 128 + colBase + c)) * 8;
  half8 bf0 = *(const half8*)(bn1base);
  half8 bf1 = *(const half8*)(bn1base + 128);
  #pragma unroll
  for (int ks = 0; ks < 8; ++ks) {
    half8 nb0, nb1;
    if (ks < 7) {
      nb0 = *(const half8*)(bn1base + (ks + 1) * 4096);
      nb1 = *(const half8*)(bn1base + (ks + 1) * 4096 + 128);
    }
    #pragma unroll
    for (int mt = 0; mt < 2; ++mt) {
      half8 a = *(const half8*)&Y[(mt * 16 + c) * YS + ks * 32 + q * 8];
      acc[mt][0] = __builtin_amdgcn_mfma_f32_16x16x32_f16(a, bf0, acc[mt][0], 0, 0, 0);
      acc[mt][1] = __builtin_amdgcn_mfma_f32_16x16x32_f16(a, bf1, acc[mt][1], 0, 0, 0);
    }
    bf0 = nb0; bf1 = nb1;
  }
  const f16* bn2base = BN2 + ((size_t)(q * 128 + colBase + c)) * 8;
  half8 d0 = *(const half8*)(bn2base);
  half8 d1 = *(const half8*)(bn2base + 128);
  __syncthreads();
  f16* T = Y;   // alias, stride TS
  #pragma unroll
  for (int mt = 0; mt < 2; ++mt)
    #pragma unroll
    for (int nt = 0; nt < 2; ++nt)
      #pragma unroll
      for (int r = 0; r < 4; ++r) {
        float v = acc[mt][nt][r];
        T[(mt * 16 + q * 4 + r) * TS + colBase + nt * 16 + c] = (f16)(v > 0.f ? v : 0.f);
      }
  __syncthreads();
  f32x4 m2[2][2];
  {
    float b0 = bn2[colBase + c], b1 = bn2[colBase + 16 + c];
    #pragma unroll
    for (int mt = 0; mt < 2; ++mt) {
      m2[mt][0] = (f32x4){b0, b0, b0, b0};
      m2[mt][1] = (f32x4){b1, b1, b1, b1};
    }
  }
  #pragma unroll
  for (int kk = 0; kk < 4; ++kk) {
    half8 n0, n1;
    if (kk < 3) {
      n0 = *(const half8*)(bn2base + (kk + 1) * 4096);
      n1 = *(const half8*)(bn2base + (kk + 1) * 4096 + 128);
    }
    #pragma unroll
    for (int mt = 0; mt < 2; ++mt) {
      half8 a = *(const half8*)&T[(mt * 16 + c) * TS + kk * 32 + q * 8];
      m2[mt][0] = __builtin_amdgcn_mfma_f32_16x16x32_f16(a, d0, m2[mt][0], 0, 0, 0);
      m2[mt][1] = __builtin_amdgcn_mfma_f32_16x16x32_f16(a, d1, m2[mt][1], 0, 0, 0);
    }
    d0 = n0; d1 = n1;
  }
  #pragma unroll
  for (int mt = 0; mt < 2; ++mt)
    #pragma unroll
    for (int r = 0; r < 4; ++r) {
      int g = n0 + mt * 16 + q * 4 + r;
      if (g < N_NODES) {
        float* o = out + (size_t)g * HID + colBase + c;
        o[0]  = m2[mt][0][r];
        o[16] = m2[mt][1][r];
      }
    }
}

extern "C" void kernel_launch(void* const* d_in, const int* in_sizes, int n_in,
                              void* d_out, int out_size, void* d_ws, size_t ws_size,
                              hipStream_t stream) {
  const float* h    = (const float*)d_in[0];
  const int*   eidx = (const int*)d_in[1];
  const float* eattr= (const float*)d_in[2];
  const float* We1  = (const float*)d_in[3];
  const float* be1  = (const float*)d_in[4];
  const float* We2  = (const float*)d_in[5];
  const float* be2  = (const float*)d_in[6];
  const float* Wg   = (const float*)d_in[7];
  const float* bg   = (const float*)d_in[8];
  const float* Wn1  = (const float*)d_in[9];
  const float* bn1  = (const float*)d_in[10];
  const float* Wn2  = (const float*)d_in[11];
  const float* bn2  = (const float*)d_in[12];
  float* out = (float*)d_out;
  char* ws = (char*)d_ws;

  if (ws_size >= CSR_TOTAL) {
    float* mi  = (float*)(ws + OFF_MI);
    f16* h16   = (f16*)(ws + OFF_H16C);
    f16* Wp    = (f16*)(ws + OFF_WC);
    int* cnt   = (int*)(ws + OFF_CNT);
    int* cur   = (int*)(ws + OFF_CUR);
    int4* e4   = (int4*)(ws + OFF_E4);
    f16* P     = (f16*)out;   // P dead before node_kernel writes out

    pack_weights<<<400, 256, 0, stream>>>(We1, We2, Wn1, Wn2, Wp, cnt, mi);
    precompute_kernel<<<(N_NODES + NB - 1) / NB, 256, 0, stream>>>(h, eidx, Wp, P, h16, cnt);
    scan_kernel<<<49, 256, 0, stream>>>(cnt, cur);
    fill_perm<<<3125, 256, 0, stream>>>(eidx, cur, e4);
    edge_kernel<<<N_EDGES / EB, 256, 0, stream>>>(P, eidx, eattr, Wp, be1, be2,
                                                  Wg, bg, mi, e4);
    node_kernel<<<(N_NODES + NB - 1) / NB, 256, 0, stream>>>(mi, h16, Wp, bn1, bn2, out);
  } else {
    float* mi  = (float*)(ws + OFF_FMI);
    f16*   h16 = (f16*)(ws + OFF_FH16);
    f16*   Wp  = (f16*)(ws + OFF_FW);
    f16*   P   = (f16*)out;   // P dead before node_kernel writes out

    pack_weights<<<400, 256, 0, stream>>>(We1, We2, Wn1, Wn2, Wp, nullptr, mi);
    precompute_kernel<<<(N_NODES + NB - 1) / NB, 256, 0, stream>>>(h, eidx, Wp, P, h16, nullptr);
    edge_kernel<<<N_EDGES / EB, 256, 0, stream>>>(P, eidx, eattr, Wp, be1, be2,
                                                  Wg, bg, mi, nullptr);
    node_kernel<<<(N_NODES + NB - 1) / NB, 256, 0, stream>>>(mi, h16, Wp, bn1, bn2, out);
  }
}

// Round 8
// 399.902 us; speedup vs baseline: 1.0639x; 1.0639x over previous
//
#include <hip/hip_runtime.h>

#define N_NODES 50000
#define N_EDGES 800000
#define HID 128

typedef _Float16 f16;
typedef _Float16 half8 __attribute__((ext_vector_type(8)));
typedef _Float16 half4 __attribute__((ext_vector_type(4)));
typedef _Float16 half2v __attribute__((ext_vector_type(2)));
typedef float f32x4 __attribute__((ext_vector_type(4)));
typedef float f32x2 __attribute__((ext_vector_type(2)));

// ---- CSR-path workspace layout (bytes). P (f16 [50000][256]) lives in d_out. ----
#define OFF_MI     0UL             // 50000*128*4 = 25,600,000 (f32 aggregate, zeroed in pack)
#define OFF_H16C   25600000UL      // 12,800,000
#define OFF_WC     38400000UL      // packed weights: 204,800
#define OFF_CNT    38604800UL      // 50176*4 = 200,704
#define OFF_CUR    38805504UL      // 200,704
#define OFF_E4     39006208UL      // 800000*16 = 12,800,000  (CSR-ordered {eid,dst,src,pad})
#define CSR_TOTAL  51806208UL

// ---- fallback (atomic-path) layout ----
#define OFF_FMI  0UL
#define OFF_FH16 25600000UL
#define OFF_FW   38400000UL

#define WB1 0
#define WB2 36864
#define WN1 53248
#define WN2 86016

#define TS 136   // S16/T tile stride (f16)
#define YS 264   // node Y tile stride (256 + pad)
#define PS 264   // precompute stage stride (f16): 256 + pad
#define AS 40    // attr tile stride (f16): 24 attr + 8 zero + pad

#define EB 32    // edges per block (32 -> ~12KB LDS -> 8 blocks/CU)
#define NB 32    // nodes per block for precompute/node

// pack weights into B-fragment layout; zero cnt and mi
__global__ __launch_bounds__(256) void pack_weights(
    const float* __restrict__ We1, const float* __restrict__ We2,
    const float* __restrict__ Wn1, const float* __restrict__ Wn2,
    f16* __restrict__ W, int* __restrict__ cnt, float* __restrict__ mi) {
  int i = blockIdx.x * 256 + threadIdx.x;   // 0..102399
  if (cnt && i < 50176) cnt[i] = 0;
  if (mi) {
    f32x4 z = {0.f, 0.f, 0.f, 0.f};
    for (int j = i; j < N_NODES * HID / 4; j += 102400)
      ((f32x4*)mi)[j] = z;
  }
  if (i < 36864) {                          // We1 (rows permuted: h first, attr last)
    int j = i & 7, n = (i >> 3) & 127, qk = i >> 10;
    int k = qk * 8 + j;
    float v = 0.f;
    if (k < 256) v = We1[(24 + k) * 128 + n];
    else if (k < 280) v = We1[(k - 256) * 128 + n];
    W[WB1 + i] = (f16)v;
  } else if (i < 53248) {                   // We2
    int l = i - 36864;
    int j = l & 7, n = (l >> 3) & 127, qk = l >> 10;
    W[WB2 + l] = (f16)We2[(qk * 8 + j) * 128 + n];
  } else if (i < 86016) {                   // Wn1
    int l = i - 53248;
    int j = l & 7, n = (l >> 3) & 127, qk = l >> 10;
    W[WN1 + l] = (f16)Wn1[(qk * 8 + j) * 128 + n];
  } else if (i < 102400) {                  // Wn2
    int l = i - 86016;
    int j = l & 7, n = (l >> 3) & 127, qk = l >> 10;
    W[WN2 + l] = (f16)Wn2[(qk * 8 + j) * 128 + n];
  }
}

// ==== single-kernel coalesced scan of cnt[50176] -> cur (exclusive prefix).
//      49 blocks; block b redundantly sums cnt[0..b*1024) for its base. ====
__global__ __launch_bounds__(256) void scan_kernel(const int* __restrict__ cnt,
                                                   int* __restrict__ cur) {
  __shared__ int red[4];
  __shared__ int wsum[4];
  int t = threadIdx.x, b = blockIdx.x;
  int lane = t & 63, w = t >> 6;
  int s0 = 0;
  for (int i = t * 4; i < b * 1024; i += 1024) {
    int4 v = *(const int4*)(cnt + i);
    s0 += v.x + v.y + v.z + v.w;
  }
  #pragma unroll
  for (int off = 32; off; off >>= 1) s0 += __shfl_down(s0, off, 64);
  if (lane == 0) red[w] = s0;
  __syncthreads();
  int base_all = red[0] + red[1] + red[2] + red[3];
  int base = b * 1024 + t * 4;
  int4 v = *(const int4*)(cnt + base);
  int s = v.x + v.y + v.z + v.w;
  int inc = s;
  #pragma unroll
  for (int off = 1; off < 64; off <<= 1) {
    int u = __shfl_up(inc, off, 64);
    if (lane >= off) inc += u;
  }
  if (lane == 63) wsum[w] = inc;
  __syncthreads();
  int wbase = 0;
  for (int i = 0; i < w; ++i) wbase += wsum[i];
  int excl = base_all + wbase + inc - s;
  int4 o;
  o.x = excl; o.y = excl + v.x; o.z = o.y + v.y; o.w = o.z + v.z;
  *(int4*)(cur + base) = o;
}

// CSR edge records: e4[csr_pos] = {edge id, dst, src, 0}
__global__ __launch_bounds__(256) void fill_perm(
    const int* __restrict__ eidx, int* __restrict__ cur, int4* __restrict__ e4) {
  int i = blockIdx.x * 256 + threadIdx.x;   // 0..799999 exactly
  int d = eidx[i];
  int s = eidx[N_EDGES + i];
  int p = atomicAdd(&cur[d], 1);
  int4 rec; rec.x = i; rec.y = d; rec.z = s; rec.w = 0;
  e4[p] = rec;
}

// ==== precompute (32 nodes/block): h f32->f16 (writes h16), degree histogram,
//      P[n][0:128] = h[n]@We1[24:152], P[n][128:256] = h[n]@We1[152:280] (f16).
//      P written via LDS re-stage -> coalesced half8 (16B/lane) stores. ====
__global__ __launch_bounds__(256, 8) void precompute_kernel(
    const float* __restrict__ h, const int* __restrict__ eidx,
    const f16* __restrict__ Wp, f16* __restrict__ P,
    f16* __restrict__ h16, int* __restrict__ cnt) {
  __shared__ f16 Y[NB * PS];   // 16,896B: staging (stride PS) then P re-stage
  int t = threadIdx.x;
  int n0 = blockIdx.x * NB;
  {
    int rb = t >> 4, ch = t & 15;
    #pragma unroll
    for (int p = 0; p < 2; ++p) {
      int r = p * 16 + rb;
      int g = n0 + r; if (g >= N_NODES) g = N_NODES - 1;
      const float4* s4 = (const float4*)(h + (size_t)g * HID + ch * 8);
      float4 a = s4[0], b = s4[1];
      half8 v = {(f16)a.x, (f16)a.y, (f16)a.z, (f16)a.w,
                 (f16)b.x, (f16)b.y, (f16)b.z, (f16)b.w};
      *(half8*)&Y[r * PS + ch * 8] = v;
      *(half8*)(h16 + (size_t)g * HID + ch * 8) = v;
    }
  }
  // fused degree histogram (grid-stride over edges)
  if (cnt) {
    for (int i = blockIdx.x * 256 + t; i < N_EDGES; i += gridDim.x * 256)
      atomicAdd(&cnt[eidx[i]], 1);
  }
  __syncthreads();
  int w = t >> 6, lane = t & 63, q = lane >> 4, c = lane & 15;
  int colBase = w * 32;
  const f16* B = Wp + WB1 + ((size_t)(q * 128 + colBase + c)) * 8;
  f32x4 aD[2][2], aS[2][2];
  #pragma unroll
  for (int mt = 0; mt < 2; ++mt) {
    aD[mt][0] = (f32x4){0, 0, 0, 0}; aD[mt][1] = (f32x4){0, 0, 0, 0};
    aS[mt][0] = (f32x4){0, 0, 0, 0}; aS[mt][1] = (f32x4){0, 0, 0, 0};
  }
  #pragma unroll
  for (int ks = 0; ks < 4; ++ks) {
    half8 bD0 = *(const half8*)(B + ks * 4096);
    half8 bD1 = *(const half8*)(B + ks * 4096 + 128);
    half8 bS0 = *(const half8*)(B + (ks + 4) * 4096);
    half8 bS1 = *(const half8*)(B + (ks + 4) * 4096 + 128);
    #pragma unroll
    for (int mt = 0; mt < 2; ++mt) {
      half8 a = *(const half8*)&Y[(mt * 16 + c) * PS + ks * 32 + q * 8];
      aD[mt][0] = __builtin_amdgcn_mfma_f32_16x16x32_f16(a, bD0, aD[mt][0], 0, 0, 0);
      aD[mt][1] = __builtin_amdgcn_mfma_f32_16x16x32_f16(a, bD1, aD[mt][1], 0, 0, 0);
      aS[mt][0] = __builtin_amdgcn_mfma_f32_16x16x32_f16(a, bS0, aS[mt][0], 0, 0, 0);
      aS[mt][1] = __builtin_amdgcn_mfma_f32_16x16x32_f16(a, bS1, aS[mt][1], 0, 0, 0);
    }
  }
  // re-stage into Y at [row][0..255] (staging data dead; sync first), then coalesced copy-out
  __syncthreads();
  #pragma unroll
  for (int mt = 0; mt < 2; ++mt)
    #pragma unroll
    for (int r = 0; r < 4; ++r) {
      int row = mt * 16 + q * 4 + r;
      f16* o = &Y[row * PS + colBase];
      o[c]            = (f16)aD[mt][0][r];
      o[c + 16]       = (f16)aD[mt][1][r];
      o[c + 128]      = (f16)aS[mt][0][r];
      o[c + 128 + 16] = (f16)aS[mt][1][r];
    }
  __syncthreads();
  #pragma unroll
  for (int i = 0; i < 4; ++i) {
    int idx = i * 256 + t;          // 0..1023
    int row = idx >> 5;             // 0..31
    int off = (idx & 31) * 8;       // 0..248
    int g = n0 + row;
    if (g < N_NODES)
      *(half8*)(P + (size_t)g * 256 + off) = *(const half8*)&Y[row * PS + off];
  }
}

// ==== edge kernel (32 edges/block, XCD-swizzled blocks): CSR-ordered e4 records.
//      Layer1 = attr@Wa (K=32 MFMA) + f16 (Pd[dst]+Ps[src]) packed adds.
//      Epilogue (R5 form): per-col scalar run-reduction, 2x16 rows -> atomicAdd mi. ====
__global__ __launch_bounds__(256, 8) void edge_kernel(
    const f16* __restrict__ P, const int* __restrict__ eidx,
    const float* __restrict__ eattr,
    const f16* __restrict__ Wp, const float* __restrict__ be1,
    const float* __restrict__ be2,
    const float* __restrict__ Wg, const float* __restrict__ bg,
    float* __restrict__ mi, const int4* __restrict__ e4) {
  __shared__ f16 S16[EB * TS];       // 8,704B  (f16 Pd+Ps sums; T aliases this)
  __shared__ f16 A[EB * AS];         // 2,560B  (attr, 24 + 8 zeros)
  __shared__ float part[EB * 4];
  __shared__ float eijL[EB];
  __shared__ int dstL[EB];
  int t = threadIdx.x;
  // XCD-aware swizzle: 25000 blocks = 8 XCDs x 3125 contiguous CSR chunks each.
  int bid = (blockIdx.x & 7) * 3125 + (blockIdx.x >> 3);
  int e0 = bid * EB;

  if (t < EB) dstL[t] = e4 ? e4[e0 + t].y : eidx[e0 + t];

  // ---- stage S16 = Pd[dst] + Ps[src] (f16, packed adds) ----
  {
    int rb = t >> 4, ch = t & 15;
    #pragma unroll
    for (int p = 0; p < 2; ++p) {
      int r = p * 16 + rb;
      int d, s;
      if (e4) {
        int4 rec = e4[e0 + r];       // 16B broadcast across the 16 lanes of this row
        d = rec.y; s = rec.z;
      } else {
        d = eidx[e0 + r]; s = eidx[N_EDGES + e0 + r];
      }
      half8 pd = *(const half8*)(P + (size_t)d * 256 + ch * 8);
      half8 ps = *(const half8*)(P + (size_t)s * 256 + 128 + ch * 8);
      *(half8*)&S16[r * TS + ch * 8] = pd + ps;
    }
  }
  // ---- stage edge_attr (cols 0..23), zeros 24..31 ----
  if (t < 192) {
    int el = t / 6, kk = t % 6;
    int e = e4 ? e4[e0 + el].x : (e0 + el);
    float4 f = *(const float4*)(eattr + (size_t)e * 24 + kk * 4);
    half4 hv = {(f16)f.x, (f16)f.y, (f16)f.z, (f16)f.w};
    *(half4*)&A[el * AS + kk * 4] = hv;
  }
  if (t < EB) { uint4 z = {0, 0, 0, 0}; *(uint4*)&A[t * AS + 24] = z; }
  __syncthreads();

  int w = t >> 6, lane = t & 63, q = lane >> 4, c = lane & 15;
  int colBase = w * 32;

  // ---- layer 1: attr GEMM (K=32, WB1 block k=256..287) + S16 add ----
  f32x4 acc[2][2];
  {
    float b0 = be1[colBase + c], b1 = be1[colBase + 16 + c];
    #pragma unroll
    for (int mt = 0; mt < 2; ++mt) {
      acc[mt][0] = (f32x4){b0, b0, b0, b0};
      acc[mt][1] = (f32x4){b1, b1, b1, b1};
    }
  }
  {
    const f16* bA = Wp + WB1 + 32768 + ((size_t)(q * 128 + colBase + c)) * 8;
    half8 b0f = *(const half8*)(bA);
    half8 b1f = *(const half8*)(bA + 128);
    #pragma unroll
    for (int mt = 0; mt < 2; ++mt) {
      half8 a = *(const half8*)&A[(mt * 16 + c) * AS + q * 8];
      acc[mt][0] = __builtin_amdgcn_mfma_f32_16x16x32_f16(a, b0f, acc[mt][0], 0, 0, 0);
      acc[mt][1] = __builtin_amdgcn_mfma_f32_16x16x32_f16(a, b1f, acc[mt][1], 0, 0, 0);
    }
  }
  #pragma unroll
  for (int mt = 0; mt < 2; ++mt)
    #pragma unroll
    for (int r = 0; r < 4; ++r) {
      const f16* sr = &S16[(mt * 16 + q * 4 + r) * TS + colBase + c];
      acc[mt][0][r] += (float)sr[0];
      acc[mt][1][r] += (float)sr[16];
    }

  const f16* bp2base = Wp + WB2 + ((size_t)(q * 128 + colBase + c)) * 8;
  half8 d0 = *(const half8*)(bp2base);
  half8 d1 = *(const half8*)(bp2base + 128);

  __syncthreads();
  f16* T = S16;   // alias (S16 dead from here; same stride TS)
  #pragma unroll
  for (int mt = 0; mt < 2; ++mt)
    #pragma unroll
    for (int nt = 0; nt < 2; ++nt)
      #pragma unroll
      for (int r = 0; r < 4; ++r) {
        float v = acc[mt][nt][r];
        T[(mt * 16 + q * 4 + r) * TS + colBase + nt * 16 + c] = (f16)(v > 0.f ? v : 0.f);
      }
  __syncthreads();

  // ---- layer 2 ----
  f32x4 m2[2][2];
  {
    float b0 = be2[colBase + c], b1 = be2[colBase + 16 + c];
    #pragma unroll
    for (int mt = 0; mt < 2; ++mt) {
      m2[mt][0] = (f32x4){b0, b0, b0, b0};
      m2[mt][1] = (f32x4){b1, b1, b1, b1};
    }
  }
  #pragma unroll
  for (int kk = 0; kk < 4; ++kk) {
    half8 n0, n1;
    if (kk < 3) {
      n0 = *(const half8*)(bp2base + (kk + 1) * 4096);
      n1 = *(const half8*)(bp2base + (kk + 1) * 4096 + 128);
    }
    #pragma unroll
    for (int mt = 0; mt < 2; ++mt) {
      half8 a = *(const half8*)&T[(mt * 16 + c) * TS + kk * 32 + q * 8];
      m2[mt][0] = __builtin_amdgcn_mfma_f32_16x16x32_f16(a, d0, m2[mt][0], 0, 0, 0);
      m2[mt][1] = __builtin_amdgcn_mfma_f32_16x16x32_f16(a, d1, m2[mt][1], 0, 0, 0);
    }
    d0 = n0; d1 = n1;
  }

  // ---- relu + gate ----
  float wg0 = Wg[colBase + c], wg1 = Wg[colBase + 16 + c];
  float pd[2][4];
  #pragma unroll
  for (int mt = 0; mt < 2; ++mt)
    #pragma unroll
    for (int r = 0; r < 4; ++r) {
      float v0 = m2[mt][0][r]; v0 = v0 > 0.f ? v0 : 0.f; m2[mt][0][r] = v0;
      float v1 = m2[mt][1][r]; v1 = v1 > 0.f ? v1 : 0.f; m2[mt][1][r] = v1;
      pd[mt][r] = v0 * wg0 + v1 * wg1;
    }
  #pragma unroll
  for (int off = 1; off < 16; off <<= 1)
    #pragma unroll
    for (int mt = 0; mt < 2; ++mt)
      #pragma unroll
      for (int r = 0; r < 4; ++r)
        pd[mt][r] += __shfl_xor(pd[mt][r], off, 64);
  if (c == 0)
    #pragma unroll
    for (int mt = 0; mt < 2; ++mt)
      #pragma unroll
      for (int r = 0; r < 4; ++r)
        part[(mt * 16 + q * 4 + r) * 4 + w] = pd[mt][r];
  __syncthreads();
  if (t < EB) {
    float s = part[t * 4] + part[t * 4 + 1] + part[t * 4 + 2] + part[t * 4 + 3] + bg[0];
    eijL[t] = 1.f / (1.f + __expf(-s));
  }
  __syncthreads();

  if (e4) {
    // ---- write gated rows to T, then per-col run-reduce (2x16 rows) -> atomicAdd mi ----
    #pragma unroll
    for (int mt = 0; mt < 2; ++mt)
      #pragma unroll
      for (int r = 0; r < 4; ++r) {
        int el = mt * 16 + q * 4 + r;
        float ev = eijL[el];
        T[el * TS + colBase + c]      = (f16)(m2[mt][0][r] * ev);
        T[el * TS + colBase + 16 + c] = (f16)(m2[mt][1][r] * ev);
      }
    __syncthreads();
    int col = t & 127, half = t >> 7;
    int r0 = half * 16;
    float acc2 = 0.f;
    int dprev = dstL[r0];
    #pragma unroll
    for (int r2 = 0; r2 < 16; ++r2) {
      int rr = r0 + r2;
      acc2 += (float)T[rr * TS + col];
      int dnext = (r2 == 15) ? -1 : dstL[rr + 1];
      if (dnext != dprev) {
        atomicAdd(&mi[(size_t)dprev * HID + col], acc2);
        acc2 = 0.f;
        dprev = dnext;
      }
    }
  } else {
    #pragma unroll
    for (int mt = 0; mt < 2; ++mt)
      #pragma unroll
      for (int r = 0; r < 4; ++r) {
        int el = mt * 16 + q * 4 + r;
        float ev = eijL[el];
        float* base = mi + (size_t)dstL[el] * HID + colBase + c;
        atomicAdd(base,      m2[mt][0][r] * ev);
        atomicAdd(base + 16, m2[mt][1][r] * ev);
      }
  }
}

// ==== node MLP kernel (32 nodes/block): reads f32 mi (ws) + h16, writes out. ====
__global__ __launch_bounds__(256, 8) void node_kernel(
    const float* __restrict__ mi, const f16* __restrict__ h16,
    const f16* __restrict__ Wp, const float* __restrict__ bn1,
    const float* __restrict__ bn2, float* __restrict__ out) {
  __shared__ f16 Y[NB * YS];   // 16,896B
  int t = threadIdx.x;
  int n0 = blockIdx.x * NB;
  {
    int rb = t >> 4, ch = t & 15;
    #pragma unroll
    for (int p = 0; p < 2; ++p) {
      int r = p * 16 + rb;
      int g = n0 + r; if (g >= N_NODES) g = N_NODES - 1;
      const float4* s = (const float4*)(mi + (size_t)g * HID + ch * 8);
      float4 a = s[0], b = s[1];
      half8 v = {(f16)a.x, (f16)a.y, (f16)a.z, (f16)a.w,
                 (f16)b.x, (f16)b.y, (f16)b.z, (f16)b.w};
      *(half8*)&Y[r * YS + ch * 8] = v;
      *(uint4*)&Y[r * YS + 128 + ch * 8] = *(const uint4*)(h16 + (size_t)g * HID + ch * 8);
    }
  }
  __syncthreads();
  int w = t >> 6, lane = t & 63, q = lane >> 4, c = lane & 15;
  int colBase = w * 32;
  const f16* BN1 = Wp + WN1;
  const f16* BN2 = Wp + WN2;
  f32x4 acc[2][2];
  {
    float b0 = bn1[colBase + c], b1 = bn1[colBase + 16 + c];
    #pragma unroll
    for (int mt = 0; mt < 2; ++mt) {
      acc[mt][0] = (f32x4){b0, b0, b0, b0};
      acc[mt][1] = (f32x4){b1, b1, b1, b1};
    }
  }
  const f16* bn1base = BN1 + ((size_t)(q * 128 + colBase + c)) * 8;
  half8 bf0 = *(const half8*)(bn1base);
  half8 bf1 = *(const half8*)(bn1base + 128);
  #pragma unroll
  for (int ks = 0; ks < 8; ++ks) {
    half8 nb0, nb1;
    if (ks < 7) {
      nb0 = *(const half8*)(bn1base + (ks + 1) * 4096);
      nb1 = *(const half8*)(bn1base + (ks + 1) * 4096 + 128);
    }
    #pragma unroll
    for (int mt = 0; mt < 2; ++mt) {
      half8 a = *(const half8*)&Y[(mt * 16 + c) * YS + ks * 32 + q * 8];
      acc[mt][0] = __builtin_amdgcn_mfma_f32_16x16x32_f16(a, bf0, acc[mt][0], 0, 0, 0);
      acc[mt][1] = __builtin_amdgcn_mfma_f32_16x16x32_f16(a, bf1, acc[mt][1], 0, 0, 0);
    }
    bf0 = nb0; bf1 = nb1;
  }
  const f16* bn2base = BN2 + ((size_t)(q * 128 + colBase + c)) * 8;
  half8 d0 = *(const half8*)(bn2base);
  half8 d1 = *(const half8*)(bn2base + 128);
  __syncthreads();
  f16* T = Y;   // alias, stride TS
  #pragma unroll
  for (int mt = 0; mt < 2; ++mt)
    #pragma unroll
    for (int nt = 0; nt < 2; ++nt)
      #pragma unroll
      for (int r = 0; r < 4; ++r) {
        float v = acc[mt][nt][r];
        T[(mt * 16 + q * 4 + r) * TS + colBase + nt * 16 + c] = (f16)(v > 0.f ? v : 0.f);
      }
  __syncthreads();
  f32x4 m2[2][2];
  {
    float b0 = bn2[colBase + c], b1 = bn2[colBase + 16 + c];
    #pragma unroll
    for (int mt = 0; mt < 2; ++mt) {
      m2[mt][0] = (f32x4){b0, b0, b0, b0};
      m2[mt][1] = (f32x4){b1, b1, b1, b1};
    }
  }
  #pragma unroll
  for (int kk = 0; kk < 4; ++kk) {
    half8 n0, n1;
    if (kk < 3) {
      n0 = *(const half8*)(bn2base + (kk + 1) * 4096);
      n1 = *(const half8*)(bn2base + (kk + 1) * 4096 + 128);
    }
    #pragma unroll
    for (int mt = 0; mt < 2; ++mt) {
      half8 a = *(const half8*)&T[(mt * 16 + c) * TS + kk * 32 + q * 8];
      m2[mt][0] = __builtin_amdgcn_mfma_f32_16x16x32_f16(a, d0, m2[mt][0], 0, 0, 0);
      m2[mt][1] = __builtin_amdgcn_mfma_f32_16x16x32_f16(a, d1, m2[mt][1], 0, 0, 0);
    }
    d0 = n0; d1 = n1;
  }
  #pragma unroll
  for (int mt = 0; mt < 2; ++mt)
    #pragma unroll
    for (int r = 0; r < 4; ++r) {
      int g = n0 + mt * 16 + q * 4 + r;
      if (g < N_NODES) {
        float* o = out + (size_t)g * HID + colBase + c;
        o[0]  = m2[mt][0][r];
        o[16] = m2[mt][1][r];
      }
    }
}

extern "C" void kernel_launch(void* const* d_in, const int* in_sizes, int n_in,
                              void* d_out, int out_size, void* d_ws, size_t ws_size,
                              hipStream_t stream) {
  const float* h    = (const float*)d_in[0];
  const int*   eidx = (const int*)d_in[1];
  const float* eattr= (const float*)d_in[2];
  const float* We1  = (const float*)d_in[3];
  const float* be1  = (const float*)d_in[4];
  const float* We2  = (const float*)d_in[5];
  const float* be2  = (const float*)d_in[6];
  const float* Wg   = (const float*)d_in[7];
  const float* bg   = (const float*)d_in[8];
  const float* Wn1  = (const float*)d_in[9];
  const float* bn1  = (const float*)d_in[10];
  const float* Wn2  = (const float*)d_in[11];
  const float* bn2  = (const float*)d_in[12];
  float* out = (float*)d_out;
  char* ws = (char*)d_ws;

  if (ws_size >= CSR_TOTAL) {
    float* mi  = (float*)(ws + OFF_MI);
    f16* h16   = (f16*)(ws + OFF_H16C);
    f16* Wp    = (f16*)(ws + OFF_WC);
    int* cnt   = (int*)(ws + OFF_CNT);
    int* cur   = (int*)(ws + OFF_CUR);
    int4* e4   = (int4*)(ws + OFF_E4);
    f16* P     = (f16*)out;   // P dead before node_kernel writes out

    pack_weights<<<400, 256, 0, stream>>>(We1, We2, Wn1, Wn2, Wp, cnt, mi);
    precompute_kernel<<<(N_NODES + NB - 1) / NB, 256, 0, stream>>>(h, eidx, Wp, P, h16, cnt);
    scan_kernel<<<49, 256, 0, stream>>>(cnt, cur);
    fill_perm<<<3125, 256, 0, stream>>>(eidx, cur, e4);
    edge_kernel<<<N_EDGES / EB, 256, 0, stream>>>(P, eidx, eattr, Wp, be1, be2,
                                                  Wg, bg, mi, e4);
    node_kernel<<<(N_NODES + NB - 1) / NB, 256, 0, stream>>>(mi, h16, Wp, bn1, bn2, out);
  } else {
    float* mi  = (float*)(ws + OFF_FMI);
    f16*   h16 = (f16*)(ws + OFF_FH16);
    f16*   Wp  = (f16*)(ws + OFF_FW);
    f16*   P   = (f16*)out;   // P dead before node_kernel writes out

    pack_weights<<<400, 256, 0, stream>>>(We1, We2, Wn1, Wn2, Wp, nullptr, mi);
    precompute_kernel<<<(N_NODES + NB - 1) / NB, 256, 0, stream>>>(h, eidx, Wp, P, h16, nullptr);
    edge_kernel<<<N_EDGES / EB, 256, 0, stream>>>(P, eidx, eattr, Wp, be1, be2,
                                                  Wg, bg, mi, nullptr);
    node_kernel<<<(N_NODES + NB - 1) / NB, 256, 0, stream>>>(mi, h16, Wp, bn1, bn2, out);
  }
}

// Round 9
// 377.865 us; speedup vs baseline: 1.1260x; 1.0583x over previous
//
#include <hip/hip_runtime.h>

#define N_NODES 50000
#define N_EDGES 800000
#define HID 128

typedef _Float16 f16;
typedef _Float16 half8 __attribute__((ext_vector_type(8)));
typedef _Float16 half4 __attribute__((ext_vector_type(4)));
typedef _Float16 half2v __attribute__((ext_vector_type(2)));
typedef float f32x4 __attribute__((ext_vector_type(4)));
typedef float f32x2 __attribute__((ext_vector_type(2)));

// CSR edge record: one 64B cache line per edge, fully written by fill_perm.
// bytes 0..15: dst, src, pad, pad ; bytes 16..63: attr[24] f16
struct __align__(64) ERec { int dst, src, p0, p1; f16 attr[24]; };
static_assert(sizeof(ERec) == 64, "ERec must be 64B");

// ---- CSR-path workspace layout (bytes). P (f16 [50000][256]) lives in d_out. ----
#define OFF_MI     0UL             // 50000*128*4 = 25,600,000 (f32 aggregate, zeroed in pack)
#define OFF_H16C   25600000UL      // 12,800,000
#define OFF_WC     38400000UL      // packed weights: 204,800
#define OFF_CNT    38604800UL      // 50176*4 = 200,704
#define OFF_CUR    38805504UL      // 200,704
#define OFF_E4     39006208UL      // 800000*64 = 51,200,000 (64B-aligned CSR records)
#define CSR_TOTAL  90206208UL

// ---- fallback (atomic-path) layout ----
#define OFF_FMI  0UL
#define OFF_FH16 25600000UL
#define OFF_FW   38400000UL

#define WB1 0
#define WB2 36864
#define WN1 53248
#define WN2 86016

#define TS 136   // S16/T tile stride (f16)
#define YS 264   // node Y tile stride (256 + pad)
#define AS 40    // attr tile stride (f16): 24 attr + 8 zero + pad

#define EB 32    // edges per block (8 blocks/CU)
#define NB 32    // nodes per block for precompute/node

// pack weights into B-fragment layout; zero cnt and mi
__global__ __launch_bounds__(256) void pack_weights(
    const float* __restrict__ We1, const float* __restrict__ We2,
    const float* __restrict__ Wn1, const float* __restrict__ Wn2,
    f16* __restrict__ W, int* __restrict__ cnt, float* __restrict__ mi) {
  int i = blockIdx.x * 256 + threadIdx.x;   // 0..102399
  if (cnt && i < 50176) cnt[i] = 0;
  if (mi) {
    f32x4 z = {0.f, 0.f, 0.f, 0.f};
    for (int j = i; j < N_NODES * HID / 4; j += 102400)
      ((f32x4*)mi)[j] = z;
  }
  if (i < 36864) {                          // We1 (rows permuted: h first, attr last)
    int j = i & 7, n = (i >> 3) & 127, qk = i >> 10;
    int k = qk * 8 + j;
    float v = 0.f;
    if (k < 256) v = We1[(24 + k) * 128 + n];
    else if (k < 280) v = We1[(k - 256) * 128 + n];
    W[WB1 + i] = (f16)v;
  } else if (i < 53248) {                   // We2
    int l = i - 36864;
    int j = l & 7, n = (l >> 3) & 127, qk = l >> 10;
    W[WB2 + l] = (f16)We2[(qk * 8 + j) * 128 + n];
  } else if (i < 86016) {                   // Wn1
    int l = i - 53248;
    int j = l & 7, n = (l >> 3) & 127, qk = l >> 10;
    W[WN1 + l] = (f16)Wn1[(qk * 8 + j) * 128 + n];
  } else if (i < 102400) {                  // Wn2
    int l = i - 86016;
    int j = l & 7, n = (l >> 3) & 127, qk = l >> 10;
    W[WN2 + l] = (f16)Wn2[(qk * 8 + j) * 128 + n];
  }
}

// ==== single-kernel coalesced scan of cnt[50176] -> cur (exclusive prefix).
//      49 blocks; block b redundantly sums cnt[0..b*1024) for its base. ====
__global__ __launch_bounds__(256) void scan_kernel(const int* __restrict__ cnt,
                                                   int* __restrict__ cur) {
  __shared__ int red[4];
  __shared__ int wsum[4];
  int t = threadIdx.x, b = blockIdx.x;
  int lane = t & 63, w = t >> 6;
  int s0 = 0;
  for (int i = t * 4; i < b * 1024; i += 1024) {
    int4 v = *(const int4*)(cnt + i);
    s0 += v.x + v.y + v.z + v.w;
  }
  #pragma unroll
  for (int off = 32; off; off >>= 1) s0 += __shfl_down(s0, off, 64);
  if (lane == 0) red[w] = s0;
  __syncthreads();
  int base_all = red[0] + red[1] + red[2] + red[3];
  int base = b * 1024 + t * 4;
  int4 v = *(const int4*)(cnt + base);
  int s = v.x + v.y + v.z + v.w;
  int inc = s;
  #pragma unroll
  for (int off = 1; off < 64; off <<= 1) {
    int u = __shfl_up(inc, off, 64);
    if (lane >= off) inc += u;
  }
  if (lane == 63) wsum[w] = inc;
  __syncthreads();
  int wbase = 0;
  for (int i = 0; i < w; ++i) wbase += wsum[i];
  int excl = base_all + wbase + inc - s;
  int4 o;
  o.x = excl; o.y = excl + v.x; o.z = o.y + v.y; o.w = o.z + v.z;
  *(int4*)(cur + base) = o;
}

// CSR records: e4[csr_pos] = {dst, src, attr f16}. Reads eattr coalesced (natural
// order), converts f32->f16 here, writes exactly one full 64B line per edge.
__global__ __launch_bounds__(256) void fill_perm(
    const int* __restrict__ eidx, const float* __restrict__ eattr,
    int* __restrict__ cur, ERec* __restrict__ e4) {
  int i = blockIdx.x * 256 + threadIdx.x;   // 0..799999 exactly
  int d = eidx[i];
  int s = eidx[N_EDGES + i];
  const float4* af = (const float4*)(eattr + (size_t)i * 24);
  float4 f0 = af[0], f1 = af[1], f2 = af[2], f3 = af[3], f4 = af[4], f5 = af[5];
  half8 ha = {(f16)f0.x, (f16)f0.y, (f16)f0.z, (f16)f0.w,
              (f16)f1.x, (f16)f1.y, (f16)f1.z, (f16)f1.w};
  half8 hb = {(f16)f2.x, (f16)f2.y, (f16)f2.z, (f16)f2.w,
              (f16)f3.x, (f16)f3.y, (f16)f3.z, (f16)f3.w};
  half8 hc = {(f16)f4.x, (f16)f4.y, (f16)f4.z, (f16)f4.w,
              (f16)f5.x, (f16)f5.y, (f16)f5.z, (f16)f5.w};
  int p = atomicAdd(&cur[d], 1);
  ERec* o = e4 + p;
  int4 hd; hd.x = d; hd.y = s; hd.z = 0; hd.w = 0;
  *(int4*)o = hd;                       // bytes 0..15
  *(half8*)(o->attr)      = ha;         // 16..31
  *(half8*)(o->attr + 8)  = hb;         // 32..47
  *(half8*)(o->attr + 16) = hc;         // 48..63
}

// ==== precompute (32 nodes/block): h f32->f16 (writes h16), degree histogram,
//      P[n][0:128] = h[n]@We1[24:152], P[n][128:256] = h[n]@We1[152:280] (f16). ====
__global__ __launch_bounds__(256, 8) void precompute_kernel(
    const float* __restrict__ h, const int* __restrict__ eidx,
    const f16* __restrict__ Wp, f16* __restrict__ P,
    f16* __restrict__ h16, int* __restrict__ cnt) {
  __shared__ f16 Y[NB * 136];   // 8,704B
  int t = threadIdx.x;
  int n0 = blockIdx.x * NB;
  {
    int rb = t >> 4, ch = t & 15;
    #pragma unroll
    for (int p = 0; p < 2; ++p) {
      int r = p * 16 + rb;
      int g = n0 + r; if (g >= N_NODES) g = N_NODES - 1;
      const float4* s4 = (const float4*)(h + (size_t)g * HID + ch * 8);
      float4 a = s4[0], b = s4[1];
      half8 v = {(f16)a.x, (f16)a.y, (f16)a.z, (f16)a.w,
                 (f16)b.x, (f16)b.y, (f16)b.z, (f16)b.w};
      *(half8*)&Y[r * 136 + ch * 8] = v;
      *(half8*)(h16 + (size_t)g * HID + ch * 8) = v;
    }
  }
  // fused degree histogram (grid-stride over edges)
  if (cnt) {
    for (int i = blockIdx.x * 256 + t; i < N_EDGES; i += gridDim.x * 256)
      atomicAdd(&cnt[eidx[i]], 1);
  }
  __syncthreads();
  int w = t >> 6, lane = t & 63, q = lane >> 4, c = lane & 15;
  int colBase = w * 32;
  const f16* B = Wp + WB1 + ((size_t)(q * 128 + colBase + c)) * 8;
  f32x4 aD[2][2], aS[2][2];
  #pragma unroll
  for (int mt = 0; mt < 2; ++mt) {
    aD[mt][0] = (f32x4){0, 0, 0, 0}; aD[mt][1] = (f32x4){0, 0, 0, 0};
    aS[mt][0] = (f32x4){0, 0, 0, 0}; aS[mt][1] = (f32x4){0, 0, 0, 0};
  }
  #pragma unroll
  for (int ks = 0; ks < 4; ++ks) {
    half8 bD0 = *(const half8*)(B + ks * 4096);
    half8 bD1 = *(const half8*)(B + ks * 4096 + 128);
    half8 bS0 = *(const half8*)(B + (ks + 4) * 4096);
    half8 bS1 = *(const half8*)(B + (ks + 4) * 4096 + 128);
    #pragma unroll
    for (int mt = 0; mt < 2; ++mt) {
      half8 a = *(const half8*)&Y[(mt * 16 + c) * 136 + ks * 32 + q * 8];
      aD[mt][0] = __builtin_amdgcn_mfma_f32_16x16x32_f16(a, bD0, aD[mt][0], 0, 0, 0);
      aD[mt][1] = __builtin_amdgcn_mfma_f32_16x16x32_f16(a, bD1, aD[mt][1], 0, 0, 0);
      aS[mt][0] = __builtin_amdgcn_mfma_f32_16x16x32_f16(a, bS0, aS[mt][0], 0, 0, 0);
      aS[mt][1] = __builtin_amdgcn_mfma_f32_16x16x32_f16(a, bS1, aS[mt][1], 0, 0, 0);
    }
  }
  #pragma unroll
  for (int mt = 0; mt < 2; ++mt)
    #pragma unroll
    for (int r = 0; r < 4; ++r) {
      int g = n0 + mt * 16 + q * 4 + r;
      if (g < N_NODES) {
        f16* o = P + (size_t)g * 256 + colBase + c;
        o[0]        = (f16)aD[mt][0][r];
        o[16]       = (f16)aD[mt][1][r];
        o[128]      = (f16)aS[mt][0][r];
        o[128 + 16] = (f16)aS[mt][1][r];
      }
    }
}

// ==== edge kernel (32 edges/block, XCD-swizzled): per-edge input is ONE sequential
//      64B record. Layer1 = attr@Wa (K=32 MFMA) + f16 (Pd[dst]+Ps[src]) packed adds.
//      Epilogue: per-col run-reduce (2x16 rows) -> atomicAdd mi. ====
__global__ __launch_bounds__(256, 8) void edge_kernel(
    const f16* __restrict__ P, const int* __restrict__ eidx,
    const float* __restrict__ eattr,
    const f16* __restrict__ Wp, const float* __restrict__ be1,
    const float* __restrict__ be2,
    const float* __restrict__ Wg, const float* __restrict__ bg,
    float* __restrict__ mi, const ERec* __restrict__ e4) {
  __shared__ f16 S16[EB * TS];       // 8,704B  (f16 Pd+Ps sums; T aliases this)
  __shared__ f16 A[EB * AS];         // 2,560B  (attr, 24 + 8 zeros)
  __shared__ float part[EB * 4];
  __shared__ float eijL[EB];
  __shared__ int dstL[EB];
  int t = threadIdx.x;
  // XCD-aware swizzle: 25000 blocks = 8 XCDs x 3125 contiguous CSR chunks each.
  int bid = (blockIdx.x & 7) * 3125 + (blockIdx.x >> 3);
  int e0 = bid * EB;

  if (t < EB) dstL[t] = e4 ? e4[e0 + t].dst : eidx[e0 + t];

  // ---- stage S16 = Pd[dst] + Ps[src] (f16, packed adds) ----
  {
    int rb = t >> 4, ch = t & 15;
    #pragma unroll
    for (int p = 0; p < 2; ++p) {
      int r = p * 16 + rb;
      int d, s;
      if (e4) {
        int2 hd = *(const int2*)(e4 + e0 + r);   // 8B broadcast across the row's 16 lanes
        d = hd.x; s = hd.y;
      } else {
        d = eidx[e0 + r]; s = eidx[N_EDGES + e0 + r];
      }
      half8 pd = *(const half8*)(P + (size_t)d * 256 + ch * 8);
      half8 ps = *(const half8*)(P + (size_t)s * 256 + 128 + ch * 8);
      *(half8*)&S16[r * TS + ch * 8] = pd + ps;
    }
  }
  // ---- stage edge_attr (cols 0..23): sequential 16B reads from the records ----
  if (e4) {
    if (t < 96) {
      int row = t / 3, seg = t - row * 3;
      *(half8*)&A[row * AS + seg * 8] = *(const half8*)(e4[e0 + row].attr + seg * 8);
    }
  } else {
    if (t < 192) {
      int el = t / 6, kk = t % 6;
      float4 f = *(const float4*)(eattr + (size_t)(e0 + el) * 24 + kk * 4);
      half4 hv = {(f16)f.x, (f16)f.y, (f16)f.z, (f16)f.w};
      *(half4*)&A[el * AS + kk * 4] = hv;
    }
  }
  if (t < EB) { uint4 z = {0, 0, 0, 0}; *(uint4*)&A[t * AS + 24] = z; }
  __syncthreads();

  int w = t >> 6, lane = t & 63, q = lane >> 4, c = lane & 15;
  int colBase = w * 32;

  // ---- layer 1: attr GEMM (K=32, WB1 block k=256..287) + S16 add ----
  f32x4 acc[2][2];
  {
    float b0 = be1[colBase + c], b1 = be1[colBase + 16 + c];
    #pragma unroll
    for (int mt = 0; mt < 2; ++mt) {
      acc[mt][0] = (f32x4){b0, b0, b0, b0};
      acc[mt][1] = (f32x4){b1, b1, b1, b1};
    }
  }
  {
    const f16* bA = Wp + WB1 + 32768 + ((size_t)(q * 128 + colBase + c)) * 8;
    half8 b0f = *(const half8*)(bA);
    half8 b1f = *(const half8*)(bA + 128);
    #pragma unroll
    for (int mt = 0; mt < 2; ++mt) {
      half8 a = *(const half8*)&A[(mt * 16 + c) * AS + q * 8];
      acc[mt][0] = __builtin_amdgcn_mfma_f32_16x16x32_f16(a, b0f, acc[mt][0], 0, 0, 0);
      acc[mt][1] = __builtin_amdgcn_mfma_f32_16x16x32_f16(a, b1f, acc[mt][1], 0, 0, 0);
    }
  }
  #pragma unroll
  for (int mt = 0; mt < 2; ++mt)
    #pragma unroll
    for (int r = 0; r < 4; ++r) {
      const f16* sr = &S16[(mt * 16 + q * 4 + r) * TS + colBase + c];
      acc[mt][0][r] += (float)sr[0];
      acc[mt][1][r] += (float)sr[16];
    }

  const f16* bp2base = Wp + WB2 + ((size_t)(q * 128 + colBase + c)) * 8;
  half8 d0 = *(const half8*)(bp2base);
  half8 d1 = *(const half8*)(bp2base + 128);

  __syncthreads();
  f16* T = S16;   // alias (S16 dead from here; same stride TS)
  #pragma unroll
  for (int mt = 0; mt < 2; ++mt)
    #pragma unroll
    for (int nt = 0; nt < 2; ++nt)
      #pragma unroll
      for (int r = 0; r < 4; ++r) {
        float v = acc[mt][nt][r];
        T[(mt * 16 + q * 4 + r) * TS + colBase + nt * 16 + c] = (f16)(v > 0.f ? v : 0.f);
      }
  __syncthreads();

  // ---- layer 2 ----
  f32x4 m2[2][2];
  {
    float b0 = be2[colBase + c], b1 = be2[colBase + 16 + c];
    #pragma unroll
    for (int mt = 0; mt < 2; ++mt) {
      m2[mt][0] = (f32x4){b0, b0, b0, b0};
      m2[mt][1] = (f32x4){b1, b1, b1, b1};
    }
  }
  #pragma unroll
  for (int kk = 0; kk < 4; ++kk) {
    half8 n0, n1;
    if (kk < 3) {
      n0 = *(const half8*)(bp2base + (kk + 1) * 4096);
      n1 = *(const half8*)(bp2base + (kk + 1) * 4096 + 128);
    }
    #pragma unroll
    for (int mt = 0; mt < 2; ++mt) {
      half8 a = *(const half8*)&T[(mt * 16 + c) * TS + kk * 32 + q * 8];
      m2[mt][0] = __builtin_amdgcn_mfma_f32_16x16x32_f16(a, d0, m2[mt][0], 0, 0, 0);
      m2[mt][1] = __builtin_amdgcn_mfma_f32_16x16x32_f16(a, d1, m2[mt][1], 0, 0, 0);
    }
    d0 = n0; d1 = n1;
  }

  // ---- relu + gate ----
  float wg0 = Wg[colBase + c], wg1 = Wg[colBase + 16 + c];
  float pd[2][4];
  #pragma unroll
  for (int mt = 0; mt < 2; ++mt)
    #pragma unroll
    for (int r = 0; r < 4; ++r) {
      float v0 = m2[mt][0][r]; v0 = v0 > 0.f ? v0 : 0.f; m2[mt][0][r] = v0;
      float v1 = m2[mt][1][r]; v1 = v1 > 0.f ? v1 : 0.f; m2[mt][1][r] = v1;
      pd[mt][r] = v0 * wg0 + v1 * wg1;
    }
  #pragma unroll
  for (int off = 1; off < 16; off <<= 1)
    #pragma unroll
    for (int mt = 0; mt < 2; ++mt)
      #pragma unroll
      for (int r = 0; r < 4; ++r)
        pd[mt][r] += __shfl_xor(pd[mt][r], off, 64);
  if (c == 0)
    #pragma unroll
    for (int mt = 0; mt < 2; ++mt)
      #pragma unroll
      for (int r = 0; r < 4; ++r)
        part[(mt * 16 + q * 4 + r) * 4 + w] = pd[mt][r];
  __syncthreads();
  if (t < EB) {
    float s = part[t * 4] + part[t * 4 + 1] + part[t * 4 + 2] + part[t * 4 + 3] + bg[0];
    eijL[t] = 1.f / (1.f + __expf(-s));
  }
  __syncthreads();

  if (e4) {
    // ---- write gated rows to T, then per-col run-reduce (2x16 rows) -> atomicAdd mi ----
    #pragma unroll
    for (int mt = 0; mt < 2; ++mt)
      #pragma unroll
      for (int r = 0; r < 4; ++r) {
        int el = mt * 16 + q * 4 + r;
        float ev = eijL[el];
        T[el * TS + colBase + c]      = (f16)(m2[mt][0][r] * ev);
        T[el * TS + colBase + 16 + c] = (f16)(m2[mt][1][r] * ev);
      }
    __syncthreads();
    int col = t & 127, half = t >> 7;
    int r0 = half * 16;
    float acc2 = 0.f;
    int dprev = dstL[r0];
    #pragma unroll
    for (int r2 = 0; r2 < 16; ++r2) {
      int rr = r0 + r2;
      acc2 += (float)T[rr * TS + col];
      int dnext = (r2 == 15) ? -1 : dstL[rr + 1];
      if (dnext != dprev) {
        atomicAdd(&mi[(size_t)dprev * HID + col], acc2);
        acc2 = 0.f;
        dprev = dnext;
      }
    }
  } else {
    #pragma unroll
    for (int mt = 0; mt < 2; ++mt)
      #pragma unroll
      for (int r = 0; r < 4; ++r) {
        int el = mt * 16 + q * 4 + r;
        float ev = eijL[el];
        float* base = mi + (size_t)dstL[el] * HID + colBase + c;
        atomicAdd(base,      m2[mt][0][r] * ev);
        atomicAdd(base + 16, m2[mt][1][r] * ev);
      }
  }
}

// ==== node MLP kernel (32 nodes/block): reads f32 mi (ws) + h16, writes out. ====
__global__ __launch_bounds__(256, 8) void node_kernel(
    const float* __restrict__ mi, const f16* __restrict__ h16,
    const f16* __restrict__ Wp, const float* __restrict__ bn1,
    const float* __restrict__ bn2, float* __restrict__ out) {
  __shared__ f16 Y[NB * YS];   // 16,896B
  int t = threadIdx.x;
  int n0 = blockIdx.x * NB;
  {
    int rb = t >> 4, ch = t & 15;
    #pragma unroll
    for (int p = 0; p < 2; ++p) {
      int r = p * 16 + rb;
      int g = n0 + r; if (g >= N_NODES) g = N_NODES - 1;
      const float4* s = (const float4*)(mi + (size_t)g * HID + ch * 8);
      float4 a = s[0], b = s[1];
      half8 v = {(f16)a.x, (f16)a.y, (f16)a.z, (f16)a.w,
                 (f16)b.x, (f16)b.y, (f16)b.z, (f16)b.w};
      *(half8*)&Y[r * YS + ch * 8] = v;
      *(uint4*)&Y[r * YS + 128 + ch * 8] = *(const uint4*)(h16 + (size_t)g * HID + ch * 8);
    }
  }
  __syncthreads();
  int w = t >> 6, lane = t & 63, q = lane >> 4, c = lane & 15;
  int colBase = w * 32;
  const f16* BN1 = Wp + WN1;
  const f16* BN2 = Wp + WN2;
  f32x4 acc[2][2];
  {
    float b0 = bn1[colBase + c], b1 = bn1[colBase + 16 + c];
    #pragma unroll
    for (int mt = 0; mt < 2; ++mt) {
      acc[mt][0] = (f32x4){b0, b0, b0, b0};
      acc[mt][1] = (f32x4){b1, b1, b1, b1};
    }
  }
  const f16* bn1base = BN1 + ((size_t)(q * 128 + colBase + c)) * 8;
  half8 bf0 = *(const half8*)(bn1base);
  half8 bf1 = *(const half8*)(bn1base + 128);
  #pragma unroll
  for (int ks = 0; ks < 8; ++ks) {
    half8 nb0, nb1;
    if (ks < 7) {
      nb0 = *(const half8*)(bn1base + (ks + 1) * 4096);
      nb1 = *(const half8*)(bn1base + (ks + 1) * 4096 + 128);
    }
    #pragma unroll
    for (int mt = 0; mt < 2; ++mt) {
      half8 a = *(const half8*)&Y[(mt * 16 + c) * YS + ks * 32 + q * 8];
      acc[mt][0] = __builtin_amdgcn_mfma_f32_16x16x32_f16(a, bf0, acc[mt][0], 0, 0, 0);
      acc[mt][1] = __builtin_amdgcn_mfma_f32_16x16x32_f16(a, bf1, acc[mt][1], 0, 0, 0);
    }
    bf0 = nb0; bf1 = nb1;
  }
  const f16* bn2base = BN2 + ((size_t)(q * 128 + colBase + c)) * 8;
  half8 d0 = *(const half8*)(bn2base);
  half8 d1 = *(const half8*)(bn2base + 128);
  __syncthreads();
  f16* T = Y;   // alias, stride TS
  #pragma unroll
  for (int mt = 0; mt < 2; ++mt)
    #pragma unroll
    for (int nt = 0; nt < 2; ++nt)
      #pragma unroll
      for (int r = 0; r < 4; ++r) {
        float v = acc[mt][nt][r];
        T[(mt * 16 + q * 4 + r) * TS + colBase + nt * 16 + c] = (f16)(v > 0.f ? v : 0.f);
      }
  __syncthreads();
  f32x4 m2[2][2];
  {
    float b0 = bn2[colBase + c], b1 = bn2[colBase + 16 + c];
    #pragma unroll
    for (int mt = 0; mt < 2; ++mt) {
      m2[mt][0] = (f32x4){b0, b0, b0, b0};
      m2[mt][1] = (f32x4){b1, b1, b1, b1};
    }
  }
  #pragma unroll
  for (int kk = 0; kk < 4; ++kk) {
    half8 n0, n1;
    if (kk < 3) {
      n0 = *(const half8*)(bn2base + (kk + 1) * 4096);
      n1 = *(const half8*)(bn2base + (kk + 1) * 4096 + 128);
    }
    #pragma unroll
    for (int mt = 0; mt < 2; ++mt) {
      half8 a = *(const half8*)&T[(mt * 16 + c) * TS + kk * 32 + q * 8];
      m2[mt][0] = __builtin_amdgcn_mfma_f32_16x16x32_f16(a, d0, m2[mt][0], 0, 0, 0);
      m2[mt][1] = __builtin_amdgcn_mfma_f32_16x16x32_f16(a, d1, m2[mt][1], 0, 0, 0);
    }
    d0 = n0; d1 = n1;
  }
  #pragma unroll
  for (int mt = 0; mt < 2; ++mt)
    #pragma unroll
    for (int r = 0; r < 4; ++r) {
      int g = n0 + mt * 16 + q * 4 + r;
      if (g < N_NODES) {
        float* o = out + (size_t)g * HID + colBase + c;
        o[0]  = m2[mt][0][r];
        o[16] = m2[mt][1][r];
      }
    }
}

extern "C" void kernel_launch(void* const* d_in, const int* in_sizes, int n_in,
                              void* d_out, int out_size, void* d_ws, size_t ws_size,
                              hipStream_t stream) {
  const float* h    = (const float*)d_in[0];
  const int*   eidx = (const int*)d_in[1];
  const float* eattr= (const float*)d_in[2];
  const float* We1  = (const float*)d_in[3];
  const float* be1  = (const float*)d_in[4];
  const float* We2  = (const float*)d_in[5];
  const float* be2  = (const float*)d_in[6];
  const float* Wg   = (const float*)d_in[7];
  const float* bg   = (const float*)d_in[8];
  const float* Wn1  = (const float*)d_in[9];
  const float* bn1  = (const float*)d_in[10];
  const float* Wn2  = (const float*)d_in[11];
  const float* bn2  = (const float*)d_in[12];
  float* out = (float*)d_out;
  char* ws = (char*)d_ws;

  if (ws_size >= CSR_TOTAL) {
    float* mi  = (float*)(ws + OFF_MI);
    f16* h16   = (f16*)(ws + OFF_H16C);
    f16* Wp    = (f16*)(ws + OFF_WC);
    int* cnt   = (int*)(ws + OFF_CNT);
    int* cur   = (int*)(ws + OFF_CUR);
    ERec* e4   = (ERec*)(ws + OFF_E4);
    f16* P     = (f16*)out;   // P dead before node_kernel writes out

    pack_weights<<<400, 256, 0, stream>>>(We1, We2, Wn1, Wn2, Wp, cnt, mi);
    precompute_kernel<<<(N_NODES + NB - 1) / NB, 256, 0, stream>>>(h, eidx, Wp, P, h16, cnt);
    scan_kernel<<<49, 256, 0, stream>>>(cnt, cur);
    fill_perm<<<3125, 256, 0, stream>>>(eidx, eattr, cur, e4);
    edge_kernel<<<N_EDGES / EB, 256, 0, stream>>>(P, eidx, eattr, Wp, be1, be2,
                                                  Wg, bg, mi, e4);
    node_kernel<<<(N_NODES + NB - 1) / NB, 256, 0, stream>>>(mi, h16, Wp, bn1, bn2, out);
  } else {
    float* mi  = (float*)(ws + OFF_FMI);
    f16*   h16 = (f16*)(ws + OFF_FH16);
    f16*   Wp  = (f16*)(ws + OFF_FW);
    f16*   P   = (f16*)out;   // P dead before node_kernel writes out

    pack_weights<<<400, 256, 0, stream>>>(We1, We2, Wn1, Wn2, Wp, nullptr, mi);
    precompute_kernel<<<(N_NODES + NB - 1) / NB, 256, 0, stream>>>(h, eidx, Wp, P, h16, nullptr);
    edge_kernel<<<N_EDGES / EB, 256, 0, stream>>>(P, eidx, eattr, Wp, be1, be2,
                                                  Wg, bg, mi, nullptr);
    node_kernel<<<(N_NODES + NB - 1) / NB, 256, 0, stream>>>(mi, h16, Wp, bn1, bn2, out);
  }
}